// Round 4
// baseline (202.585 us; speedup 1.0000x reference)
//
#include <hip/hip_runtime.h>

// ---------------------------------------------------------------------------
// QuantizedShaper: B=256, L=8192, DIM=256, NPAT=64, HIST=32, WIN=8, T=1024.
//
//   scores[t,b,p] = clip( sum_h xpad[b, t*8+h] * W2[p,h] + bias2[p], 0, 6 )
//   out[b, t*8+w] = relu( shapes_w[w, idx[t,b]] - x[b, t*8+w] )
//
// Scan restructured (R4): butterfly runs on keyA = ordkey(r_s - t0_{s-1})
// which is computable BEFORE w_{s-1} resolves; the single lane where the true
// v differs (lane w_{s-1}, value vB) is excised from the butterfly (masked to
// 0) and resolved scalar-side: KB = readlane(keyB, w) vs K1 3-way select.
// ordkey is an exact order-preserving float->uint map, so argmax decisions
// (incl. first-index tie-break) are bit-exact vs the reference.
// ---------------------------------------------------------------------------

constexpr int Bb = 256, Ll = 8192, DIMc = 256, NPAT = 64, HIST = 32, WINc = 8;
constexpr int Tt = Ll / WINc;   // 1024
constexpr int TC = 32;          // t-chunk
constexpr int NC = Tt / TC;     // 32 chunks
constexpr float CINV = 1.0f / 64.0f;

// exact order-preserving map: a<b (float, no NaN) <=> ordkey(a)<ordkey(b)
__device__ __forceinline__ unsigned ordkey(float v) {
  int b = __float_as_int(v);
  return (unsigned)(b ^ ((b >> 31) | 0x80000000));
}

#define DPP_MAXU(m, ctrl)                                                      \
  do {                                                                         \
    unsigned _t = (unsigned)__builtin_amdgcn_update_dpp(                       \
        (int)(m), (int)(m), (ctrl), 0xF, 0xF, false);                          \
    (m) = ((m) > _t) ? (m) : _t;                                               \
  } while (0)

// one block per pattern p: W2[p,0..31] + bias2[p]
__global__ __launch_bounds__(256) void precompute_kernel(
    const float* __restrict__ conv_w, const float* __restrict__ conv_b,
    const float* __restrict__ keys_w, float* __restrict__ wsf) {
  __shared__ float part[8][32];
  __shared__ float bred[4];
  const int p = blockIdx.x;
  const int t = threadIdx.x;
  const int h = t & 31, g = t >> 5;
  const float* kwp = keys_w + (size_t)p * DIMc;

  float acc = 0.f;
#pragma unroll
  for (int dd = 0; dd < 32; ++dd) {
    int d = g * 32 + dd;
    acc = fmaf(kwp[d], conv_w[d * HIST + h], acc);
  }
  part[g][h] = acc;

  float bp = kwp[t] * conv_b[t];
#pragma unroll
  for (int off = 32; off; off >>= 1) bp += __shfl_down(bp, off);
  if ((t & 63) == 0) bred[t >> 6] = bp;
  __syncthreads();

  if (t < 32) {
    float s = 0.f;
#pragma unroll
    for (int gg = 0; gg < 8; ++gg) s += part[gg][t];
    wsf[(t >> 2) * (NPAT * 4) + p * 4 + (t & 3)] = s;  // float4-friendly
  } else if (t == 32) {
    wsf[NPAT * HIST + p] = (bred[0] + bred[1]) + (bred[2] + bred[3]);
  }
}

__global__ __launch_bounds__(256) void shaper_kernel(
    const float* __restrict__ x, const float* __restrict__ avg_init,
    const float* __restrict__ shapes_w, const float* __restrict__ wsf,
    float* __restrict__ out) {
  __shared__ __align__(16) float xpad[HIST - 1 + Ll + 1];
  __shared__ float scb[2][TC * NPAT];
  __shared__ int   idxb[Tt];
  __shared__ float shp[WINc * NPAT];

  const int b    = blockIdx.x;
  const int tid  = threadIdx.x;
  const int wid  = tid >> 6;
  const int lane = tid & 63;
  const float* xrow = x + (size_t)b * Ll;

  // ---- stage x (left-padded) + shapes into LDS ----
  if (tid < HIST - 1) xpad[tid] = 0.f;
  {
    const float4* xv4 = (const float4*)xrow;
#pragma unroll
    for (int k = 0; k < 8; ++k) {
      int i4 = k * 256 + tid;
      float4 v = xv4[i4];
      float* dst = xpad + HIST - 1 + i4 * 4;
      dst[0] = v.x; dst[1] = v.y; dst[2] = v.z; dst[3] = v.w;
    }
  }
  for (int i = tid; i < WINc * NPAT; i += 256) shp[i] = shapes_w[i];

  // ---- per-role setup ----
  float4 w2v[8];
  float  b2 = 0.f;
  if (wid > 0) {
    const float4* w2g = (const float4*)wsf;
#pragma unroll
    for (int h4 = 0; h4 < 8; ++h4) w2v[h4] = w2g[h4 * 64 + lane];
    b2 = wsf[NPAT * HIST + lane];
  }
  float av0 = 0.f;
  if (wid == 0) {
    const float* ai = avg_init + (size_t)b * NPAT;
    float s = 0.f;
    for (int j = 0; j < NPAT; ++j) s += ai[j];
    av0 = ai[lane] - s * (1.0f / NPAT);  // avg0 = avg_init - mean
  }
  __syncthreads();

  // score tile for chunk c (waves 1..3)
  auto fill = [&](int c, float* __restrict__ sb) {
    int base = c * TC;
    for (int tl = wid - 1; tl < TC; tl += 3) {
      int t = base + tl;
      const float4* xw = (const float4*)(xpad + t * WINc);  // 32B-aligned
      float acc = b2;
#pragma unroll
      for (int h4 = 0; h4 < 8; ++h4) {
        float4 xv = xw[h4];
        float4 wv = w2v[h4];
        acc = fmaf(xv.x, wv.x, acc);
        acc = fmaf(xv.y, wv.y, acc);
        acc = fmaf(xv.z, wv.z, acc);
        acc = fmaf(xv.w, wv.w, acc);
      }
      sb[tl * NPAT + lane] = fminf(fmaxf(acc, 0.f), 6.f);  // relu6
    }
  };

  // ---- scan state (wave 0), carried across chunks ----
  // wS: previous winner (64 = none). t0/t1: av candidates for current step.
  int   wS = 64;
  float t0 = av0, t1 = av0;

  // scan one 32-step chunk. keyA/keyB for the chunk's first step are built
  // here (r of this chunk only valid after the barrier).
  auto scan_chunk = [&](const float* __restrict__ sb, int tbase) {
    float r[TC];
#pragma unroll
    for (int i = 0; i < TC; ++i) r[i] = sb[i * NPAT + lane];
    unsigned keyA = ordkey(r[0] - t0);
    unsigned keyB = ordkey(r[0] - t1);
    int stash = 0;
#pragma unroll
    for (int i = 0; i < TC; ++i) {
      // ---- critical chain ----
      bool isw = (lane == wS);
      unsigned keym0 = isw ? 0u : keyA;   // excise patched lane (keys > 0)
      unsigned m = keym0;
      DPP_MAXU(m, 0xB1);   // xor1 (quad_perm 1,0,3,2)
      DPP_MAXU(m, 0x4E);   // xor2 (quad_perm 2,3,0,1)
      DPP_MAXU(m, 0x141);  // row_half_mirror (xor4)
      DPP_MAXU(m, 0x140);  // row_mirror (xor8) -> row-16 max in every lane
      unsigned m0 = (unsigned)__builtin_amdgcn_readlane((int)m, 15);
      unsigned m1 = (unsigned)__builtin_amdgcn_readlane((int)m, 31);
      unsigned m2 = (unsigned)__builtin_amdgcn_readlane((int)m, 47);
      unsigned m3 = (unsigned)__builtin_amdgcn_readlane((int)m, 63);
      unsigned ka = m0 > m1 ? m0 : m1;
      unsigned kb = m2 > m3 ? m2 : m3;
      unsigned K1 = ka > kb ? ka : kb;    // max over lanes != wS
      unsigned KB = (unsigned)__builtin_amdgcn_readlane((int)keyB, wS);
      unsigned long long bal = __ballot(keym0 == K1);
      int I1 = __ffsll(bal) - 1;          // first-index among lanes != wS
      // 3-way resolve of the patched lane (exact, incl. first-index ties)
      int wnew = (KB > K1) ? wS : ((KB == K1) ? (wS < I1 ? wS : I1) : I1);

      // ---- off-chain: exact reference-order av update + next-step spec ----
      float av = isw ? t1 : t0;           // av for step just resolved... (s)
      t0 = av - CINV;                     // == (av + 0) - 1/64 exactly
      t1 = (av + 1.0f) - CINV;            // winner path, reference fp order
      if (i + 1 < TC) {
        keyA = ordkey(r[i + 1] - t0);
        keyB = ordkey(r[i + 1] - t1);
      }
      stash = (lane == i) ? wnew : stash;
      wS = wnew;
    }
    if (lane < TC) idxb[tbase + lane] = stash;
  };

  // ---- pipeline: wave0 scans chunk c, waves1-3 fill chunk c+1 ----
  if (wid > 0) fill(0, scb[0]);
  __syncthreads();

  for (int c = 0; c < NC; ++c) {
    if (wid == 0) {
      scan_chunk(scb[c & 1], c * TC);
    } else if (c + 1 < NC) {
      fill(c + 1, scb[(c + 1) & 1]);
    }
    __syncthreads();
  }

  // ---- epilogue: out[b,l] = relu(shapes[l&7, idx[l>>3]] - x[b,l]) ----
  float4* outv = (float4*)(out + (size_t)b * Ll);
#pragma unroll
  for (int k = 0; k < 8; ++k) {
    int i4 = k * 256 + tid;
    int l0 = i4 * 4;
    int t  = l0 >> 3;
    int w0 = l0 & 7;
    int p  = idxb[t];
    float4 o;
    o.x = fmaxf(shp[(w0 + 0) * NPAT + p] - xpad[HIST - 1 + l0 + 0], 0.f);
    o.y = fmaxf(shp[(w0 + 1) * NPAT + p] - xpad[HIST - 1 + l0 + 1], 0.f);
    o.z = fmaxf(shp[(w0 + 2) * NPAT + p] - xpad[HIST - 1 + l0 + 2], 0.f);
    o.w = fmaxf(shp[(w0 + 3) * NPAT + p] - xpad[HIST - 1 + l0 + 3], 0.f);
    outv[i4] = o;
  }
}

extern "C" void kernel_launch(void* const* d_in, const int* in_sizes, int n_in,
                              void* d_out, int out_size, void* d_ws, size_t ws_size,
                              hipStream_t stream) {
  const float* x        = (const float*)d_in[0];
  const float* avg_init = (const float*)d_in[1];
  const float* conv_w   = (const float*)d_in[2];
  const float* conv_b   = (const float*)d_in[3];
  const float* keys_w   = (const float*)d_in[4];
  const float* shapes_w = (const float*)d_in[5];
  float* wsf = (float*)d_ws;

  precompute_kernel<<<NPAT, 256, 0, stream>>>(conv_w, conv_b, keys_w, wsf);
  shaper_kernel<<<Bb, 256, 0, stream>>>(x, avg_init, shapes_w, wsf,
                                        (float*)d_out);
}